// Round 1
// baseline (80.848 us; speedup 1.0000x reference)
//
#include <hip/hip_runtime.h>

#define NN 320
#define DFULL 129            // 1 time dim + 128 spatial
#define MIN_DIST_F 0.1f
#define MARGIN_F 0.1f
#define WEIGHT_F 0.1f
#define NPAIRS (NN*(NN-1)/2) // 51040

// ---------------- Kernel 1: Lorentz pairwise arccosh distances ----------------
// emb[i*NN+j] = acoshf(max(t_i*t_j - sp_i . sp_j, 1+1e-7))
// Also zeroes the 2-word accumulator (block 0,0).
__global__ __launch_bounds__(256) void lorentz_kernel(const float* __restrict__ E,
                                                      float* __restrict__ emb,
                                                      float* __restrict__ acc) {
    if (blockIdx.x == 0 && blockIdx.y == 0 && threadIdx.x < 2) {
        acc[threadIdx.x] = 0.0f;   // total (f32) and count (u32 bit-pattern 0)
    }
    __shared__ float As[16][DFULL];
    __shared__ float Bs[16][DFULL];
    const int i0 = blockIdx.y * 16;
    const int j0 = blockIdx.x * 16;
    for (int t = threadIdx.x; t < 16 * DFULL; t += 256) {
        int r = t / DFULL, c = t - r * DFULL;
        As[r][c] = E[(i0 + r) * DFULL + c];
        Bs[r][c] = E[(j0 + r) * DFULL + c];
    }
    __syncthreads();
    const int ti = threadIdx.x & 15;     // j within tile
    const int tj = threadIdx.x >> 4;     // i within tile
    float tt = As[tj][0] * Bs[ti][0];    // t_i * t_j
    float ss = 0.0f;                     // sp_i . sp_j
    #pragma unroll
    for (int d = 1; d < DFULL; d++) ss = fmaf(As[tj][d], Bs[ti][d], ss);
    float x = fmaxf(tt - ss, 1.0f + 1e-7f);
    emb[(i0 + tj) * NN + (j0 + ti)] = acoshf(x);
}

// ---------------- Kernel 2: rank-order violation accumulation ----------------
// grid.x = anchor i, grid.y = pair-space chunks.
__global__ __launch_bounds__(256) void loss_kernel(const float* __restrict__ emb,
                                                   const float* __restrict__ gt,
                                                   float* __restrict__ acc) {
    const int i = blockIdx.x;
    __shared__ float se[NN];
    __shared__ float sg[NN];   // gt value, or -1 if invalid (diag or < MIN_DIST)
    for (int t = threadIdx.x; t < NN; t += 256) {
        se[t] = emb[i * NN + t];
        float g = gt[i * NN + t];
        sg[t] = (g >= MIN_DIST_F && t != i) ? g : -1.0f;
    }
    __syncthreads();

    float total = 0.0f;
    unsigned cnt = 0;
    const int stride = gridDim.y * 256;
    for (int p = blockIdx.y * 256 + threadIdx.x; p < NPAIRS; p += stride) {
        // tournament bijection: rectangle [0,NN/2) x [0,NN-1) -> strict upper triangle
        int r = p / (NN - 1);
        int c = p - r * (NN - 1);
        int j, k;
        if (c >= r) { j = r;          k = c + 1; }
        else        { j = NN - 1 - r; k = NN - 1 - c; }
        float gj = sg[j], gk = sg[k];
        if (gj < 0.0f || gk < 0.0f) continue;     // validity mask
        float d = gk - gj;
        if (d == 0.0f) continue;                  // s == 0
        float s = (d > 0.0f) ? 1.0f : -1.0f;
        float v = fmaf(s, se[j] - se[k], MARGIN_F);
        if (v > 0.0f) { total += v; cnt++; }
    }

    // wave64 shuffle reduce
    for (int off = 32; off > 0; off >>= 1) {
        total += __shfl_down(total, off, 64);
        cnt   += __shfl_down(cnt,   off, 64);
    }
    __shared__ float    wt[4];
    __shared__ unsigned wc[4];
    const int lane = threadIdx.x & 63, wid = threadIdx.x >> 6;
    if (lane == 0) { wt[wid] = total; wc[wid] = cnt; }
    __syncthreads();
    if (threadIdx.x == 0) {
        float    T = wt[0] + wt[1] + wt[2] + wt[3];
        unsigned C = wc[0] + wc[1] + wc[2] + wc[3];
        atomicAdd(&acc[0], T);
        atomicAdd((unsigned*)&acc[1], C);
    }
}

// ---------------- Kernel 3: finalize scalar loss ----------------
__global__ void finalize_kernel(const float* __restrict__ acc, float* __restrict__ out) {
    float    T = acc[0];
    unsigned C = *(const unsigned*)&acc[1];
    out[0] = (C > 0) ? WEIGHT_F * T / (float)C : 0.0f;
}

extern "C" void kernel_launch(void* const* d_in, const int* in_sizes, int n_in,
                              void* d_out, int out_size, void* d_ws, size_t ws_size,
                              hipStream_t stream) {
    const float* E  = (const float*)d_in[0];   // embeddings (320 x 129)
    const float* gt = (const float*)d_in[1];   // tree_distances (320 x 320)
    float* out = (float*)d_out;
    float* acc = (float*)d_ws;                          // 2 words
    float* emb = (float*)((char*)d_ws + 256);           // 320*320 f32 = 400 KB

    dim3 g1(20, 20);
    lorentz_kernel<<<g1, 256, 0, stream>>>(E, emb, acc);
    dim3 g2(NN, 8);
    loss_kernel<<<g2, 256, 0, stream>>>(emb, gt, acc);
    finalize_kernel<<<1, 1, 0, stream>>>(acc, out);
}

// Round 2
// 28.004 us; speedup vs baseline: 2.8870x; 2.8870x over previous
//
#include <hip/hip_runtime.h>

#define NN 320
#define DFULL 129            // 1 time dim + 128 spatial
#define MIN_DIST_F 0.1f
#define MARGIN_F 0.1f
#define WEIGHT_F 0.1f
#define NPAIRS (NN*(NN-1)/2) // 51040
#define CHUNKS 8
#define NBLK (NN*CHUNKS)     // 2560 loss blocks

// ---------------- Kernel 1: Lorentz pairwise arccosh distances ----------------
// emb[i*NN+j] = acoshf(max(t_i*t_j - sp_i . sp_j, 1+1e-7))
__global__ __launch_bounds__(256) void lorentz_kernel(const float* __restrict__ E,
                                                      float* __restrict__ emb) {
    __shared__ float As[16][DFULL];
    __shared__ float Bs[16][DFULL];
    const int i0 = blockIdx.y * 16;
    const int j0 = blockIdx.x * 16;
    for (int t = threadIdx.x; t < 16 * DFULL; t += 256) {
        int r = t / DFULL, c = t - r * DFULL;
        As[r][c] = E[(i0 + r) * DFULL + c];
        Bs[r][c] = E[(j0 + r) * DFULL + c];
    }
    __syncthreads();
    const int ti = threadIdx.x & 15;     // j within tile
    const int tj = threadIdx.x >> 4;     // i within tile
    float tt = As[tj][0] * Bs[ti][0];    // t_i * t_j
    float ss = 0.0f;                     // sp_i . sp_j
    #pragma unroll
    for (int d = 1; d < DFULL; d++) ss = fmaf(As[tj][d], Bs[ti][d], ss);
    float x = fmaxf(tt - ss, 1.0f + 1e-7f);
    emb[(i0 + tj) * NN + (j0 + ti)] = acoshf(x);
}

// ---------------- Kernel 2: rank-order violations -> per-block partials ----------------
// grid.x = anchor i (320), grid.y = pair chunk (8). partial[bid] = {total, count}.
__global__ __launch_bounds__(256) void loss_kernel(const float* __restrict__ emb,
                                                   const float* __restrict__ gt,
                                                   float2* __restrict__ partial) {
    const int i = blockIdx.x;
    __shared__ float se[NN];
    __shared__ float sg[NN];   // gt value, or -1 if invalid (diag or < MIN_DIST)
    for (int t = threadIdx.x; t < NN; t += 256) {
        se[t] = emb[i * NN + t];
        float g = gt[i * NN + t];
        sg[t] = (g >= MIN_DIST_F && t != i) ? g : -1.0f;
    }
    __syncthreads();

    float total = 0.0f;
    float cnt = 0.0f;
    const int stride = CHUNKS * 256;
    for (int p = blockIdx.y * 256 + threadIdx.x; p < NPAIRS; p += stride) {
        // tournament bijection: rectangle [0,NN/2) x [0,NN-1) -> strict upper triangle
        int r = p / (NN - 1);
        int c = p - r * (NN - 1);
        int j, k;
        if (c >= r) { j = r;          k = c + 1; }
        else        { j = NN - 1 - r; k = NN - 1 - c; }
        float gj = sg[j], gk = sg[k];
        if (gj < 0.0f || gk < 0.0f) continue;     // validity mask
        float d = gk - gj;
        if (d == 0.0f) continue;                  // s == 0
        float s = (d > 0.0f) ? 1.0f : -1.0f;
        float v = fmaf(s, se[j] - se[k], MARGIN_F);
        if (v > 0.0f) { total += v; cnt += 1.0f; }
    }

    // wave64 shuffle reduce
    for (int off = 32; off > 0; off >>= 1) {
        total += __shfl_down(total, off, 64);
        cnt   += __shfl_down(cnt,   off, 64);
    }
    __shared__ float wt[4];
    __shared__ float wc[4];
    const int lane = threadIdx.x & 63, wid = threadIdx.x >> 6;
    if (lane == 0) { wt[wid] = total; wc[wid] = cnt; }
    __syncthreads();
    if (threadIdx.x == 0) {
        float T = wt[0] + wt[1] + wt[2] + wt[3];
        float C = wc[0] + wc[1] + wc[2] + wc[3];
        partial[blockIdx.y * NN + blockIdx.x] = make_float2(T, C);
    }
}

// ---------------- Kernel 3: reduce partials, finalize scalar loss ----------------
__global__ __launch_bounds__(256) void finalize_kernel(const float2* __restrict__ partial,
                                                       float* __restrict__ out) {
    float T = 0.0f, C = 0.0f;
    for (int t = threadIdx.x; t < NBLK; t += 256) {
        float2 p = partial[t];
        T += p.x; C += p.y;
    }
    for (int off = 32; off > 0; off >>= 1) {
        T += __shfl_down(T, off, 64);
        C += __shfl_down(C, off, 64);
    }
    __shared__ float wt[4];
    __shared__ float wc[4];
    const int lane = threadIdx.x & 63, wid = threadIdx.x >> 6;
    if (lane == 0) { wt[wid] = T; wc[wid] = C; }
    __syncthreads();
    if (threadIdx.x == 0) {
        float Tt = wt[0] + wt[1] + wt[2] + wt[3];
        float Ct = wc[0] + wc[1] + wc[2] + wc[3];
        out[0] = (Ct > 0.0f) ? WEIGHT_F * Tt / Ct : 0.0f;
    }
}

extern "C" void kernel_launch(void* const* d_in, const int* in_sizes, int n_in,
                              void* d_out, int out_size, void* d_ws, size_t ws_size,
                              hipStream_t stream) {
    const float* E  = (const float*)d_in[0];   // embeddings (320 x 129)
    const float* gt = (const float*)d_in[1];   // tree_distances (320 x 320)
    float* out = (float*)d_out;
    float2* partial = (float2*)d_ws;                      // 2560 float2 = 20 KB
    float*  emb = (float*)((char*)d_ws + 32768);          // 320*320 f32 = 400 KB

    dim3 g1(20, 20);
    lorentz_kernel<<<g1, 256, 0, stream>>>(E, emb);
    dim3 g2(NN, CHUNKS);
    loss_kernel<<<g2, 256, 0, stream>>>(emb, gt, partial);
    finalize_kernel<<<1, 256, 0, stream>>>(partial, out);
}

// Round 3
// 21.559 us; speedup vs baseline: 3.7501x; 1.2990x over previous
//
#include <hip/hip_runtime.h>
#include <math.h>

#define NN 320
#define DFULL 129            // 1 time dim + 128 spatial
#define MIN_DIST_F 0.1f
#define MARGIN_F 0.1f
#define WEIGHT_F 0.1f
#define CHUNKJ 4
#define JLEN (NN / CHUNKJ)   // 80 j's per block
#define NBLK (NN * CHUNKJ)   // 1280 loss blocks = exactly 5 per CU

// ---------------- Kernel 1: Lorentz pairwise arccosh distances ----------------
__global__ __launch_bounds__(256) void lorentz_kernel(const float* __restrict__ E,
                                                      float* __restrict__ emb) {
    __shared__ float As[16][DFULL];
    __shared__ float Bs[16][DFULL];
    const int i0 = blockIdx.y * 16;
    const int j0 = blockIdx.x * 16;
    for (int t = threadIdx.x; t < 16 * DFULL; t += 256) {
        int r = t / DFULL, c = t - r * DFULL;
        As[r][c] = E[(i0 + r) * DFULL + c];
        Bs[r][c] = E[(j0 + r) * DFULL + c];
    }
    __syncthreads();
    const int ti = threadIdx.x & 15;
    const int tj = threadIdx.x >> 4;
    float tt = As[tj][0] * Bs[ti][0];
    float ss = 0.0f;
    #pragma unroll
    for (int d = 1; d < DFULL; d++) ss = fmaf(As[tj][d], Bs[ti][d], ss);
    float x = fmaxf(tt - ss, 1.0f + 1e-7f);
    emb[(i0 + tj) * NN + (j0 + ti)] = acoshf(x);
}

// ---------------- Kernel 2: ordered-pair violations -> per-block partials ----------------
// Symmetry: viol(j,k) == viol(k,j) and the mask is symmetric, so summing over
// ALL ordered pairs doubles total and count equally; total/count is unchanged.
// Lane owns k (register e_k, g_k); j-loop is a wave-uniform float2 broadcast.
// Invalid entries encode g = NaN; NaN fails (d>0 || d<0) so they drop out free.
__global__ __launch_bounds__(NN) void loss_kernel(const float* __restrict__ emb,
                                                  const float* __restrict__ gt,
                                                  float2* __restrict__ partial) {
    const int i  = blockIdx.x;        // anchor
    const int j0 = blockIdx.y * JLEN; // j-chunk
    __shared__ float2 sge[NN];
    const int t = threadIdx.x;

    float e = emb[i * NN + t];
    float g = gt[i * NN + t];
    float gm = (g >= MIN_DIST_F && t != i) ? g : __builtin_nanf("");
    sge[t] = make_float2(e, gm);
    __syncthreads();

    const float ek = e, gk = gm;      // this lane's k-side values (k == t)
    float total = 0.0f, cnt = 0.0f;
    #pragma unroll 4
    for (int j = j0; j < j0 + JLEN; ++j) {
        float2 u = sge[j];            // wave-uniform broadcast read
        float d  = gk - u.y;          // sign(g_k - g_j); NaN if either invalid
        float de = u.x - ek;          // e_j - e_k
        float s  = (d > 0.0f) ? 1.0f : -1.0f;
        float v  = fmaf(s, de, MARGIN_F);
        bool vp  = (v > 0.0f) && (d > 0.0f || d < 0.0f);  // NaN-safe, excludes d==0
        float f  = vp ? 1.0f : 0.0f;
        total = fmaf(f, v, total);
        cnt  += f;
    }

    // wave64 shuffle reduce, then 5-wave LDS reduce
    for (int off = 32; off > 0; off >>= 1) {
        total += __shfl_down(total, off, 64);
        cnt   += __shfl_down(cnt,   off, 64);
    }
    __shared__ float wt[5], wc[5];
    const int lane = t & 63, wid = t >> 6;
    if (lane == 0) { wt[wid] = total; wc[wid] = cnt; }
    __syncthreads();
    if (t == 0) {
        float T = 0.0f, C = 0.0f;
        #pragma unroll
        for (int w = 0; w < 5; w++) { T += wt[w]; C += wc[w]; }
        partial[blockIdx.y * NN + i] = make_float2(T, C);
    }
}

// ---------------- Kernel 3: reduce partials, finalize scalar loss ----------------
__global__ __launch_bounds__(256) void finalize_kernel(const float2* __restrict__ partial,
                                                       float* __restrict__ out) {
    float T = 0.0f, C = 0.0f;
    for (int t = threadIdx.x; t < NBLK; t += 256) {
        float2 p = partial[t];
        T += p.x; C += p.y;
    }
    for (int off = 32; off > 0; off >>= 1) {
        T += __shfl_down(T, off, 64);
        C += __shfl_down(C, off, 64);
    }
    __shared__ float wt[4], wc[4];
    const int lane = threadIdx.x & 63, wid = threadIdx.x >> 6;
    if (lane == 0) { wt[wid] = T; wc[wid] = C; }
    __syncthreads();
    if (threadIdx.x == 0) {
        float Tt = wt[0] + wt[1] + wt[2] + wt[3];
        float Ct = wc[0] + wc[1] + wc[2] + wc[3];
        out[0] = (Ct > 0.0f) ? WEIGHT_F * Tt / Ct : 0.0f;
    }
}

extern "C" void kernel_launch(void* const* d_in, const int* in_sizes, int n_in,
                              void* d_out, int out_size, void* d_ws, size_t ws_size,
                              hipStream_t stream) {
    const float* E  = (const float*)d_in[0];   // embeddings (320 x 129)
    const float* gt = (const float*)d_in[1];   // tree_distances (320 x 320)
    float* out = (float*)d_out;
    float2* partial = (float2*)d_ws;                      // 1280 float2 = 10 KB
    float*  emb = (float*)((char*)d_ws + 32768);          // 320*320 f32 = 400 KB

    dim3 g1(20, 20);
    lorentz_kernel<<<g1, 256, 0, stream>>>(E, emb);
    dim3 g2(NN, CHUNKJ);
    loss_kernel<<<g2, NN, 0, stream>>>(emb, gt, partial);
    finalize_kernel<<<1, 256, 0, stream>>>(partial, out);
}